// Round 13
// baseline (266.039 us; speedup 1.0000x reference)
//
#include <hip/hip_runtime.h>
#include <hip/hip_bf16.h>

#define BB 2
#define SS 2048
#define DIMM 1024
#define HH 16
#define DKK 64
// 0.125 (1/sqrt(DK)) * log2(e): folded into Q so softmax uses raw v_exp_f32 (2^x)
#define QSCALE 0.18033688011112042592f

using bf16 = __hip_bfloat16;
typedef __attribute__((ext_vector_type(8))) short v8s;
typedef __attribute__((ext_vector_type(4))) short v4s;
typedef __attribute__((ext_vector_type(4))) float f32x4;
typedef __attribute__((ext_vector_type(16))) float f32x16;

__device__ __forceinline__ int cvt_pk_bf16(float lo, float hi) {
  int r;
  asm("v_cvt_pk_bf16_f32 %0, %1, %2" : "=v"(r) : "v"(lo), "v"(hi));
  return r;
}

// load 8 consecutive fp32 and convert to a v8s bf16 fragment (RNE, same as
// the old convert kernel's __float2bfloat16 path).
__device__ __forceinline__ v8s cvt8(const float* __restrict__ p) {
  const float4 f0 = ((const float4*)p)[0];
  const float4 f1 = ((const float4*)p)[1];
  bf16 tt[8] = {__float2bfloat16(f0.x), __float2bfloat16(f0.y),
                __float2bfloat16(f0.z), __float2bfloat16(f0.w),
                __float2bfloat16(f1.x), __float2bfloat16(f1.y),
                __float2bfloat16(f1.z), __float2bfloat16(f1.w)};
  return *(const v8s*)tt;
}

// ---------------------------------------------------------------------------
// Convert/pack v2: ONLY Wob permute-convert + mask bit-packing.  The
// dec/enc/Wq/Wkv fp32->bf16 passes (~110MB of traffic) are now fused into
// proj_gemm's staging (each element converted exactly once at first touch).
// ---------------------------------------------------------------------------
__global__ __launch_bounds__(256) void convert_pack_kernel(
    const float* __restrict__ Wo, const int* __restrict__ mask,
    bf16* __restrict__ Wob, unsigned long long* __restrict__ mp) {
  const int gid = blockIdx.x * 256 + threadIdx.x;  // 0..262143
  // Wo with column permutation c' = h*64+d  <-  c = d*16+h
  if (gid < 256 * 1024) {
    const int n = gid >> 8;          // row 0..1023
    const int c4 = (gid & 255) * 4;  // dest col base (4 consecutive d)
    const int h = c4 >> 6, d0 = c4 & 63;
    const float* src = Wo + (size_t)n * DIMM + h;
    bf16 t[4];
#pragma unroll
    for (int i2 = 0; i2 < 4; ++i2)
      t[i2] = __float2bfloat16(src[(d0 + i2) * 16]);
    *(v4s*)(Wob + (size_t)n * DIMM + c4) = *(const v4s*)t;
  }
  const int lane = threadIdx.x & 63;
  const int wave_id = gid >> 6;  // 0..4095
  for (int i = 0; i < 32; ++i) {
    const size_t w = (size_t)wave_id * 32 + i;
    const unsigned long long bm = __ballot(mask[w * 64 + lane] != 0);
    if (lane == 0) {
      const int bb = (int)(w >> 16);          // batch
      const int qq = (int)((w >> 5) & 2047);  // q row
      const int kc = (int)(w & 31);           // k chunk
      mp[((size_t)bb * 32 + kc) * SS + qq] = bm;
    }
  }
}

// ---------------------------------------------------------------------------
// Merged projection GEMM v5: R9 reg-staged dbuf body, now consuming FP32
// inputs directly with in-staging bf16 conversion (fused convert kernel).
// Each staged element is read once as fp32 and converted in-register before
// the LDS write -- no bf16 intermediate in HBM.  T1 XCD remap kept (grid
// 768; g-siblings of one A-panel share an XCD L2, so the fp32 panel is
// fetched from HBM once per XCD).  R6/R11/R12 showed gload loses to this
// reg-staged structure at this shape; GEMM restructuring is closed.
// ---------------------------------------------------------------------------
__global__ __launch_bounds__(256) void proj_gemm_kernel(
    const float* __restrict__ dec, const float* __restrict__ enc,
    const float* __restrict__ Wq, const float* __restrict__ Wkv,
    bf16* __restrict__ Qr, bf16* __restrict__ Kr, bf16* __restrict__ Vt) {
  __shared__ __align__(16) bf16 As[128][72];
  __shared__ __align__(16) bf16 Bs[128][72];
  const int t = threadIdx.x;
  const int wave = t >> 6, lane = t & 63;
  const int quad = lane >> 4, l15 = lane & 15;
  const int wm = (wave >> 1) * 64, wn = (wave & 1) * 64;

  const int bid = blockIdx.x;
  const int xcd = bid & 7, slot = bid >> 3;  // slot 0..95
  const int km = xcd + 8 * (slot >> 3);      // (kind,m0) id 0..95
  const int g = slot & 7;                    // 128-col group (2 heads)
  const int kind = km >> 5;                  // 0=Q, 1=K, 2=V
  const int m0 = (km & 31) * 128;

  const int sr = t >> 2;        // staging row 0..63 (and +64)
  const int sc = (t & 3) * 16;  // staging col segment
  const int voff = (kind == 2) ? DIMM : 0;
  const int wr0 = sr * 16 + g * 2 + voff;
  const int wr1 = sr * 16 + g * 2 + 1 + voff;

  const float* arow0;
  const float* arow1;
  const float* brow0;
  const float* brow1;
  if (kind == 0) {
    arow0 = dec + (size_t)(m0 + sr) * DIMM;
    arow1 = dec + (size_t)(m0 + sr + 64) * DIMM;
    brow0 = Wq + (size_t)wr0 * DIMM;
    brow1 = Wq + (size_t)wr1 * DIMM;
  } else if (kind == 1) {
    arow0 = enc + (size_t)(m0 + sr) * DIMM;
    arow1 = enc + (size_t)(m0 + sr + 64) * DIMM;
    brow0 = Wkv + (size_t)wr0 * DIMM;
    brow1 = Wkv + (size_t)wr1 * DIMM;
  } else {
    arow0 = Wkv + (size_t)wr0 * DIMM;
    arow1 = Wkv + (size_t)wr1 * DIMM;
    brow0 = enc + (size_t)(m0 + sr) * DIMM;
    brow1 = enc + (size_t)(m0 + sr + 64) * DIMM;
  }

  v8s apf[4], bpf[4];
  auto loadAB = [&](int kc) {
    apf[0] = cvt8(arow0 + kc + sc);
    apf[1] = cvt8(arow0 + kc + sc + 8);
    apf[2] = cvt8(arow1 + kc + sc);
    apf[3] = cvt8(arow1 + kc + sc + 8);
    bpf[0] = cvt8(brow0 + kc + sc);
    bpf[1] = cvt8(brow0 + kc + sc + 8);
    bpf[2] = cvt8(brow1 + kc + sc);
    bpf[3] = cvt8(brow1 + kc + sc + 8);
  };

  f32x4 acc[4][4] = {};
  loadAB(0);

  for (int kc = 0; kc < DIMM; kc += 64) {
    __syncthreads();
    *(v8s*)&As[sr][sc] = apf[0];
    *(v8s*)&As[sr][sc + 8] = apf[1];
    *(v8s*)&As[sr + 64][sc] = apf[2];
    *(v8s*)&As[sr + 64][sc + 8] = apf[3];
    *(v8s*)&Bs[sr][sc] = bpf[0];
    *(v8s*)&Bs[sr][sc + 8] = bpf[1];
    *(v8s*)&Bs[sr + 64][sc] = bpf[2];
    *(v8s*)&Bs[sr + 64][sc + 8] = bpf[3];
    if (kc + 64 < DIMM) loadAB(kc + 64);
    __syncthreads();
#pragma unroll
    for (int ks = 0; ks < 2; ++ks) {
      v8s af[4], bfr[4];
#pragma unroll
      for (int i = 0; i < 4; ++i)
        af[i] = *(const v8s*)&As[wm + i * 16 + l15][ks * 32 + quad * 8];
#pragma unroll
      for (int j = 0; j < 4; ++j)
        bfr[j] = *(const v8s*)&Bs[wn + j * 16 + l15][ks * 32 + quad * 8];
#pragma unroll
      for (int i = 0; i < 4; ++i)
#pragma unroll
        for (int j = 0; j < 4; ++j)
          acc[i][j] = __builtin_amdgcn_mfma_f32_16x16x32_bf16(
              af[i], bfr[j], acc[i][j], 0, 0, 0);
    }
  }

#pragma unroll
  for (int i = 0; i < 4; ++i) {
#pragma unroll
    for (int r = 0; r < 4; ++r) {
      const int mm = wm + i * 16 + quad * 4 + r;  // tile-m 0..127
#pragma unroll
      for (int j = 0; j < 4; ++j) {
        const int nn = wn + j * 16 + l15;  // tile-n 0..127
        const float v = acc[i][j][r];
        if (kind == 0) {
          Qr[(size_t)(m0 + mm) * DIMM + g * 128 + nn] =
              __float2bfloat16(v * QSCALE);
        } else if (kind == 1) {
          Kr[(size_t)(m0 + mm) * DIMM + g * 128 + nn] = __float2bfloat16(v);
        } else {
          const int h = g * 2 + (mm >> 6), d = mm & 63;
          const int sn = m0 + nn;
          const int b = sn >> 11, s = sn & (SS - 1);
          Vt[(((size_t)b * HH + h) * DKK + d) * SS + s] = __float2bfloat16(v);
        }
      }
    }
  }
}

// ---------------------------------------------------------------------------
// Output projection GEMM (R9 reg-staged version -- measured best config):
// out = Ar @ Wob^T, tile 128m x 64n, BK=64, padded LDS, T1 XCD remap
// (grid 512; 16 n-siblings of each m-panel share one XCD).
// ---------------------------------------------------------------------------
__global__ __launch_bounds__(256) void out_gemm_kernel(
    const bf16* __restrict__ A, const bf16* __restrict__ W,
    float* __restrict__ out) {
  __shared__ __align__(16) bf16 As[128][72];
  __shared__ __align__(16) bf16 Bs[64][72];
  const int t = threadIdx.x;
  const int wave = t >> 6, lane = t & 63;
  const int quad = lane >> 4, l15 = lane & 15;
  const int wm = (wave >> 1) * 64, wn = (wave & 1) * 32;

  const int bid = blockIdx.x;
  const int xcd = bid & 7, slot = bid >> 3;      // slot 0..63
  const int m0 = (xcd + 8 * (slot >> 4)) * 128;  // 32 panels over 8 XCDs
  const int n0 = (slot & 15) * 64;

  const int sr = t >> 2;
  const int sc = (t & 3) * 16;

  v8s ar[4], br[2];
  auto loadA = [&](int kc) {
#pragma unroll
    for (int rr = 0; rr < 2; ++rr) {
      const bf16* p = A + (size_t)(m0 + sr + rr * 64) * DIMM + kc + sc;
#pragma unroll
      for (int i = 0; i < 2; ++i) ar[rr * 2 + i] = ((const v8s*)p)[i];
    }
  };
  auto loadB = [&](int kc) {
    const bf16* p = W + (size_t)(n0 + sr) * DIMM + kc + sc;
#pragma unroll
    for (int i = 0; i < 2; ++i) br[i] = ((const v8s*)p)[i];
  };

  f32x4 acc[4][2] = {};
  loadA(0);
  loadB(0);
  for (int kc = 0; kc < DIMM; kc += 64) {
    __syncthreads();
#pragma unroll
    for (int rr = 0; rr < 2; ++rr) {
      *(v8s*)&As[sr + rr * 64][sc] = ar[rr * 2 + 0];
      *(v8s*)&As[sr + rr * 64][sc + 8] = ar[rr * 2 + 1];
    }
    *(v8s*)&Bs[sr][sc] = br[0];
    *(v8s*)&Bs[sr][sc + 8] = br[1];
    if (kc + 64 < DIMM) {
      loadA(kc + 64);
      loadB(kc + 64);
    }
    __syncthreads();
#pragma unroll
    for (int ks = 0; ks < 2; ++ks) {
      v8s af[4], bfr[2];
#pragma unroll
      for (int i = 0; i < 4; ++i)
        af[i] = *(const v8s*)&As[wm + i * 16 + l15][ks * 32 + quad * 8];
#pragma unroll
      for (int j = 0; j < 2; ++j)
        bfr[j] = *(const v8s*)&Bs[wn + j * 16 + l15][ks * 32 + quad * 8];
#pragma unroll
      for (int i = 0; i < 4; ++i)
#pragma unroll
        for (int j = 0; j < 2; ++j)
          acc[i][j] = __builtin_amdgcn_mfma_f32_16x16x32_bf16(
              af[i], bfr[j], acc[i][j], 0, 0, 0);
    }
  }

#pragma unroll
  for (int i = 0; i < 4; ++i) {
#pragma unroll
    for (int r = 0; r < 4; ++r) {
      const int m = m0 + wm + i * 16 + quad * 4 + r;
#pragma unroll
      for (int j = 0; j < 2; ++j) {
        const int n = n0 + wn + j * 16 + l15;
        out[(size_t)m * DIMM + n] = acc[i][j][r];
      }
    }
  }
}

// ---------------------------------------------------------------------------
// MFMA flash attention v7 EXACT (best measured: 56.5-57.4us).  R4/R5/R7/R8
// all regressed it; do not touch the inner loop.
// ---------------------------------------------------------------------------
__global__ __launch_bounds__(512) void attn_kernel(
    const bf16* __restrict__ Qr, const bf16* __restrict__ Kr,
    const bf16* __restrict__ Vt, const unsigned long long* __restrict__ mp,
    bf16* __restrict__ Ar) {
  // smem[0] = K tiles, smem[1] = V tiles; [kv][parity][buf][row][col]
  __shared__ __align__(16) bf16 smem[2][2][2][64][72];

  const int t = threadIdx.x;
  const int wave = t >> 6, lane = t & 63;
  const int l31 = lane & 31, hf = lane >> 5;
  const int qb = wave & 3;   // q sub-block 0..3 (32 rows each)
  const int pr = wave >> 2;  // kt parity: 0 = even kt, 1 = odd kt

  const int bx = blockIdx.x;
  const int xcd = bx & 7, j = bx >> 3;
  const int g = (xcd << 2) | (j & 3);  // (b,h) group 0..31
  const int tile = j >> 2;             // q-tile 0..15 (128 rows each)
  const int hd = g & 15, b = g >> 4;

  const int qw = tile * 128 + qb * 32;  // wave owns 32 q-rows
  const size_t bhv = ((size_t)b * HH + hd) * DKK;

  // Q as B-fragments: lane l31 = q-col, c = cs*16 + 8*hf + i
  v8s bq[4];
  {
    const bf16* qrow = Qr + ((size_t)(b * SS + qw + l31)) * DIMM + hd * 64;
#pragma unroll
    for (int cs = 0; cs < 4; ++cs)
      bq[cs] = *(const v8s*)(qrow + cs * 16 + 8 * hf);
  }

  // ones B-fragment for row-sum MFMA
  v8s vones;
#pragma unroll
  for (int i = 0; i < 8; ++i) vones[i] = (short)0x3F80;

  f32x16 o0 = {}, o1 = {}, ol = {};

  // cooperative staging: 512 threads x 16B per tile, 4 tiles per step
  const int r0 = t >> 3;       // 0..63
  const int c0 = (t & 7) * 8;  // 0..56

  auto gK = [&](int kt) {
    return *(const v8s*)(Kr + ((size_t)(b * SS + kt * 64 + r0)) * DIMM +
                         hd * 64 + c0);
  };
  auto gV = [&](int kt) {
    return *(const v8s*)(Vt + (bhv + r0) * SS + kt * 64 + c0);
  };
  auto loadM = [&](int kt) {
    return mp[((size_t)b * 32 + kt) * SS + qw + l31];
  };

  // prologue: stage kt 0 (par0 buf0) and kt 1 (par1 buf0); prefetch kt 2,3
  {
    const v8s k0 = gK(0), v0 = gV(0), k1 = gK(1), v1 = gV(1);
    *(v8s*)&smem[0][0][0][r0][c0] = k0;
    *(v8s*)&smem[1][0][0][r0][c0] = v0;
    *(v8s*)&smem[0][1][0][r0][c0] = k1;
    *(v8s*)&smem[1][1][0][r0][c0] = v1;
  }
  v8s kpr[2], vpr[2];
  kpr[0] = gK(2);
  vpr[0] = gV(2);
  kpr[1] = gK(3);
  vpr[1] = gV(3);
  unsigned long long mwcur = loadM(pr);

  for (int s = 0; s < 16; ++s) {
    __syncthreads();
    const int nb = (s + 1) & 1;
    if (s < 15) {
      *(v8s*)&smem[0][0][nb][r0][c0] = kpr[0];
      *(v8s*)&smem[1][0][nb][r0][c0] = vpr[0];
      *(v8s*)&smem[0][1][nb][r0][c0] = kpr[1];
      *(v8s*)&smem[1][1][nb][r0][c0] = vpr[1];
      if (s < 14) {
        kpr[0] = gK(2 * s + 4);
        vpr[0] = gV(2 * s + 4);
        kpr[1] = gK(2 * s + 5);
        vpr[1] = gV(2 * s + 5);
      }
    }
    const unsigned long long mwnext = (s < 15) ? loadM(2 * s + 2 + pr) : 0ULL;
    const unsigned long long mq = mwcur >> (4 * hf);
    const int cb = s & 1;

    // ---- QK^T (swapped): st[n] rows = k (n*32 block), col = q = l31 ----
    f32x16 st[2];
#pragma unroll
    for (int n = 0; n < 2; ++n) {
      f32x16 sa = {};
#pragma unroll
      for (int cs = 0; cs < 4; ++cs) {
        const v8s ak =
            *(const v8s*)&smem[0][pr][cb][n * 32 + l31][cs * 16 + 8 * hf];
        sa = __builtin_amdgcn_mfma_f32_32x32x16_bf16(ak, bq[cs], sa, 0, 0, 0);
      }
      st[n] = sa;
    }

    // ---- masked exp2 + pack to bf16 pairs (in-register) ----
    int pd[8][2];
#pragma unroll
    for (int n = 0; n < 2; ++n)
#pragma unroll
      for (int g2 = 0; g2 < 4; ++g2)
#pragma unroll
        for (int jj = 0; jj < 2; ++jj) {
          const int bp = 32 * n + 8 * g2 + 2 * jj;
          const int m = g2 * 4 + 2 * jj;
          const float p0 =
              ((mq >> bp) & 1) ? __builtin_amdgcn_exp2f(st[n][m]) : 0.f;
          const float p1 =
              ((mq >> (bp + 1)) & 1) ? __builtin_amdgcn_exp2f(st[n][m + 1])
                                     : 0.f;
          pd[n * 4 + g2][jj] = cvt_pk_bf16(p0, p1);
        }

    // ---- redistribute to PV A-fragments: 2 permlane32_swap per k-slice ----
    v8s af[4];
#pragma unroll
    for (int ks = 0; ks < 4; ++ks) {
      int a0 = pd[2 * ks][0], b0 = pd[2 * ks + 1][0];
      int a1 = pd[2 * ks][1], b1 = pd[2 * ks + 1][1];
      asm("v_permlane32_swap_b32 %0, %1" : "+v"(a0), "+v"(b0));
      asm("v_permlane32_swap_b32 %0, %1" : "+v"(a1), "+v"(b1));
      int4 w;
      w.x = a0;
      w.y = a1;
      w.z = b0;
      w.w = b1;
      af[ks] = *(v8s*)&w;
    }

    // ---- PV + row-sum ----
#pragma unroll
    for (int ks = 0; ks < 4; ++ks) {
      const v8s bv0 = *(const v8s*)&smem[1][pr][cb][l31][ks * 16 + 8 * hf];
      const v8s bv1 =
          *(const v8s*)&smem[1][pr][cb][32 + l31][ks * 16 + 8 * hf];
      o0 = __builtin_amdgcn_mfma_f32_32x32x16_bf16(af[ks], bv0, o0, 0, 0, 0);
      o1 = __builtin_amdgcn_mfma_f32_32x32x16_bf16(af[ks], bv1, o1, 0, 0, 0);
      ol = __builtin_amdgcn_mfma_f32_32x32x16_bf16(af[ks], vones, ol, 0, 0, 0);
    }
    mwcur = mwnext;
  }

  // ---- cross-parity combine via LDS (exact sum; no running max) ----
  // scratch overlays the (now dead) K/V staging; stride 52 f32 (16B-aligned,
  // 8-bank spread) per lane.
  __syncthreads();
  float* scratch = (float*)&smem[0][0][0][0][0];
  if (wave >= 4) {
    float* dst = scratch + ((size_t)(wave - 4) * 64 + lane) * 52;
#pragma unroll
    for (int i = 0; i < 4; ++i) {
      f32x4 t0 = {o0[4 * i], o0[4 * i + 1], o0[4 * i + 2], o0[4 * i + 3]};
      f32x4 t1 = {o1[4 * i], o1[4 * i + 1], o1[4 * i + 2], o1[4 * i + 3]};
      f32x4 t2 = {ol[4 * i], ol[4 * i + 1], ol[4 * i + 2], ol[4 * i + 3]};
      *(f32x4*)(dst + 4 * i) = t0;
      *(f32x4*)(dst + 16 + 4 * i) = t1;
      *(f32x4*)(dst + 32 + 4 * i) = t2;
    }
  }
  __syncthreads();
  if (wave < 4) {
    const float* src = scratch + ((size_t)wave * 64 + lane) * 52;
#pragma unroll
    for (int m = 0; m < 16; ++m) {
      o0[m] += src[m];
      o1[m] += src[16 + m];
      ol[m] += src[32 + m];
    }
    // ---- epilogue: normalize rows and store flat [q][hd*64 + d] ----
#pragma unroll
    for (int m = 0; m < 16; ++m) {
      const float inv = __builtin_amdgcn_rcpf(ol[m]);
      const int q = qw + (m & 3) + 8 * (m >> 2) + 4 * hf;
      const size_t row = (size_t)b * SS + q;
      Ar[row * DIMM + hd * 64 + l31] = __float2bfloat16(o0[m] * inv);
      Ar[row * DIMM + hd * 64 + 32 + l31] = __float2bfloat16(o1[m] * inv);
    }
  }
}

extern "C" void kernel_launch(void* const* d_in, const int* in_sizes, int n_in,
                              void* d_out, int out_size, void* d_ws,
                              size_t ws_size, hipStream_t stream) {
  const float* dec = (const float*)d_in[0];
  const float* enc = (const float*)d_in[1];
  const float* Wq = (const float*)d_in[2];
  const float* Wkv = (const float*)d_in[3];
  const float* Wo = (const float*)d_in[4];
  const int* mask = (const int*)d_in[5];
  float* out = (float*)d_out;

  // ws layout (40.4 MB): Ar 8 MiB | (unused 6 MiB, kept for layout
  // stability) | Wob 2 | Qr 8 | Kr 8 | Vt 8 | mp 1
  char* ws = (char*)d_ws;
  size_t off = 0;
  bf16* Ar = (bf16*)(ws + off);   off += (size_t)2 * SS * DIMM * 2;
  off += (size_t)2 * DIMM * DIMM * 2;  // (was Wkvb; unused)
  bf16* Wob = (bf16*)(ws + off);  off += (size_t)DIMM * DIMM * 2;
  bf16* Qr = (bf16*)(ws + off);   off += (size_t)2 * SS * DIMM * 2;
  bf16* Kr = (bf16*)(ws + off);   off += (size_t)2 * SS * DIMM * 2;
  bf16* Vt = (bf16*)(ws + off);   off += (size_t)2 * SS * DIMM * 2;
  unsigned long long* mp = (unsigned long long*)(ws + off);

  dim3 blk(256);
  convert_pack_kernel<<<dim3(1024), blk, 0, stream>>>(Wo, mask, Wob, mp);
  proj_gemm_kernel<<<dim3(768), blk, 0, stream>>>(dec, enc, Wq, Wkv, Qr, Kr,
                                                  Vt);
  attn_kernel<<<dim3(512), dim3(512), 0, stream>>>(Qr, Kr, Vt, mp, Ar);
  out_gemm_kernel<<<dim3(512), blk, 0, stream>>>(Ar, Wob, out);
}

// Round 14
// 233.253 us; speedup vs baseline: 1.1406x; 1.1406x over previous
//
#include <hip/hip_runtime.h>
#include <hip/hip_bf16.h>

#define BB 2
#define SS 2048
#define DIMM 1024
#define HH 16
#define DKK 64
// 0.125 (1/sqrt(DK)) * log2(e): folded into Q so softmax uses raw v_exp_f32 (2^x)
#define QSCALE 0.18033688011112042592f

using bf16 = __hip_bfloat16;
typedef __attribute__((ext_vector_type(8))) short v8s;
typedef __attribute__((ext_vector_type(4))) short v4s;
typedef __attribute__((ext_vector_type(4))) float f32x4;
typedef __attribute__((ext_vector_type(16))) float f32x16;

__device__ __forceinline__ void cvt4(const float* __restrict__ s,
                                     bf16* __restrict__ d, int idx) {
  const float4 f = ((const float4*)s)[idx];
  bf16 t[4] = {__float2bfloat16(f.x), __float2bfloat16(f.y),
               __float2bfloat16(f.z), __float2bfloat16(f.w)};
  *(v4s*)(d + (size_t)idx * 4) = *(const v4s*)t;
}

__device__ __forceinline__ int cvt_pk_bf16(float lo, float hi) {
  int r;
  asm("v_cvt_pk_bf16_f32 %0, %1, %2" : "=v"(r) : "v"(lo), "v"(hi));
  return r;
}

// ---------------------------------------------------------------------------
// Fused fp32->bf16 conversion (dec, enc, Wq, Wkv, Wo) + mask bit-packing.
// Mask packed as mp[b][kt][q] (q contiguous) so attn's per-lane-q load is
// coalesced.  Wo converted with PERMUTED columns (see out_gemm).
// R13 falsified fusing these conversions into proj (fp32 staging doubled
// HBM bytes: FETCH 37->74MB, proj 65->91us).  Standalone pass is cheaper.
// ---------------------------------------------------------------------------
__global__ __launch_bounds__(256) void convert_pack_kernel(
    const float* __restrict__ dec, const float* __restrict__ enc,
    const float* __restrict__ Wq, const float* __restrict__ Wkv,
    const float* __restrict__ Wo, const int* __restrict__ mask,
    bf16* __restrict__ decb, bf16* __restrict__ encb, bf16* __restrict__ Wqb,
    bf16* __restrict__ Wkvb, bf16* __restrict__ Wob,
    unsigned long long* __restrict__ mp) {
  const int gid = blockIdx.x * 256 + threadIdx.x;  // 0..262143
  const int NT = 256 * 1024;
#pragma unroll
  for (int i = 0; i < 4; ++i) cvt4(dec, decb, gid + i * NT);
#pragma unroll
  for (int i = 0; i < 4; ++i) cvt4(enc, encb, gid + i * NT);
  cvt4(Wq, Wqb, gid);
#pragma unroll
  for (int i = 0; i < 2; ++i) cvt4(Wkv, Wkvb, gid + i * NT);
  // Wo with column permutation c' = h*64+d  <-  c = d*16+h
  {
    const int n = gid >> 8;          // row 0..1023
    const int c4 = (gid & 255) * 4;  // dest col base (4 consecutive d)
    const int h = c4 >> 6, d0 = c4 & 63;
    const float* src = Wo + (size_t)n * DIMM + h;
    bf16 t[4];
#pragma unroll
    for (int i2 = 0; i2 < 4; ++i2)
      t[i2] = __float2bfloat16(src[(d0 + i2) * 16]);
    *(v4s*)(Wob + (size_t)n * DIMM + c4) = *(const v4s*)t;
  }
  const int lane = threadIdx.x & 63;
  const int wave_id = gid >> 6;  // 0..4095
  for (int i = 0; i < 32; ++i) {
    const size_t w = (size_t)wave_id * 32 + i;
    const unsigned long long bm = __ballot(mask[w * 64 + lane] != 0);
    if (lane == 0) {
      const int bb = (int)(w >> 16);        // batch
      const int qq = (int)((w >> 5) & 2047);  // q row
      const int kc = (int)(w & 31);         // k chunk
      mp[((size_t)bb * 32 + kc) * SS + qq] = bm;
    }
  }
}

// ---------------------------------------------------------------------------
// Merged projection GEMM (reg-staged body, measured best) + T1 XCD remap:
// 1D grid 768; xcd = bid&7, slot = bid>>3; km = xcd + 8*(slot>>3) selects
// (kind,m0); g = slot&7.  All 8 g-siblings of one (kind,m0) -- which share
// the same A-panel -- land on ONE XCD's L2.  Bijective: 768 = 8 * 96.
// R6/R11/R12 showed gload variants lose to this structure at this shape.
// ---------------------------------------------------------------------------
__global__ __launch_bounds__(256) void proj_gemm_kernel(
    const bf16* __restrict__ decb, const bf16* __restrict__ encb,
    const bf16* __restrict__ Wqb, const bf16* __restrict__ Wkvb,
    bf16* __restrict__ Qr, bf16* __restrict__ Kr, bf16* __restrict__ Vt) {
  __shared__ __align__(16) bf16 As[128][72];
  __shared__ __align__(16) bf16 Bs[128][72];
  const int t = threadIdx.x;
  const int wave = t >> 6, lane = t & 63;
  const int quad = lane >> 4, l15 = lane & 15;
  const int wm = (wave >> 1) * 64, wn = (wave & 1) * 64;

  const int bid = blockIdx.x;
  const int xcd = bid & 7, slot = bid >> 3;  // slot 0..95
  const int km = xcd + 8 * (slot >> 3);      // (kind,m0) id 0..95
  const int g = slot & 7;                    // 128-col group (2 heads)
  const int kind = km >> 5;                  // 0=Q, 1=K, 2=V
  const int m0 = (km & 31) * 128;

  const int sr = t >> 2;        // staging row 0..63 (and +64)
  const int sc = (t & 3) * 16;  // staging col segment
  const int voff = (kind == 2) ? DIMM : 0;
  const int wr0 = sr * 16 + g * 2 + voff;
  const int wr1 = sr * 16 + g * 2 + 1 + voff;

  const bf16* arow0;
  const bf16* arow1;
  const bf16* brow0;
  const bf16* brow1;
  if (kind == 0) {
    arow0 = decb + (size_t)(m0 + sr) * DIMM;
    arow1 = decb + (size_t)(m0 + sr + 64) * DIMM;
    brow0 = Wqb + (size_t)wr0 * DIMM;
    brow1 = Wqb + (size_t)wr1 * DIMM;
  } else if (kind == 1) {
    arow0 = encb + (size_t)(m0 + sr) * DIMM;
    arow1 = encb + (size_t)(m0 + sr + 64) * DIMM;
    brow0 = Wkvb + (size_t)wr0 * DIMM;
    brow1 = Wkvb + (size_t)wr1 * DIMM;
  } else {
    arow0 = Wkvb + (size_t)wr0 * DIMM;
    arow1 = Wkvb + (size_t)wr1 * DIMM;
    brow0 = encb + (size_t)(m0 + sr) * DIMM;
    brow1 = encb + (size_t)(m0 + sr + 64) * DIMM;
  }

  v8s apf[4], bpf[4];
  auto loadAB = [&](int kc) {
    apf[0] = ((const v8s*)(arow0 + kc + sc))[0];
    apf[1] = ((const v8s*)(arow0 + kc + sc))[1];
    apf[2] = ((const v8s*)(arow1 + kc + sc))[0];
    apf[3] = ((const v8s*)(arow1 + kc + sc))[1];
    bpf[0] = ((const v8s*)(brow0 + kc + sc))[0];
    bpf[1] = ((const v8s*)(brow0 + kc + sc))[1];
    bpf[2] = ((const v8s*)(brow1 + kc + sc))[0];
    bpf[3] = ((const v8s*)(brow1 + kc + sc))[1];
  };

  f32x4 acc[4][4] = {};
  loadAB(0);

  for (int kc = 0; kc < DIMM; kc += 64) {
    __syncthreads();
    *(v8s*)&As[sr][sc] = apf[0];
    *(v8s*)&As[sr][sc + 8] = apf[1];
    *(v8s*)&As[sr + 64][sc] = apf[2];
    *(v8s*)&As[sr + 64][sc + 8] = apf[3];
    *(v8s*)&Bs[sr][sc] = bpf[0];
    *(v8s*)&Bs[sr][sc + 8] = bpf[1];
    *(v8s*)&Bs[sr + 64][sc] = bpf[2];
    *(v8s*)&Bs[sr + 64][sc + 8] = bpf[3];
    if (kc + 64 < DIMM) loadAB(kc + 64);
    __syncthreads();
#pragma unroll
    for (int ks = 0; ks < 2; ++ks) {
      v8s af[4], bfr[4];
#pragma unroll
      for (int i = 0; i < 4; ++i)
        af[i] = *(const v8s*)&As[wm + i * 16 + l15][ks * 32 + quad * 8];
#pragma unroll
      for (int j = 0; j < 4; ++j)
        bfr[j] = *(const v8s*)&Bs[wn + j * 16 + l15][ks * 32 + quad * 8];
#pragma unroll
      for (int i = 0; i < 4; ++i)
#pragma unroll
        for (int j = 0; j < 4; ++j)
          acc[i][j] = __builtin_amdgcn_mfma_f32_16x16x32_bf16(
              af[i], bfr[j], acc[i][j], 0, 0, 0);
    }
  }

#pragma unroll
  for (int i = 0; i < 4; ++i) {
#pragma unroll
    for (int r = 0; r < 4; ++r) {
      const int mm = wm + i * 16 + quad * 4 + r;  // tile-m 0..127
#pragma unroll
      for (int j = 0; j < 4; ++j) {
        const int nn = wn + j * 16 + l15;  // tile-n 0..127
        const float v = acc[i][j][r];
        if (kind == 0) {
          Qr[(size_t)(m0 + mm) * DIMM + g * 128 + nn] =
              __float2bfloat16(v * QSCALE);
        } else if (kind == 1) {
          Kr[(size_t)(m0 + mm) * DIMM + g * 128 + nn] = __float2bfloat16(v);
        } else {
          const int h = g * 2 + (mm >> 6), d = mm & 63;
          const int sn = m0 + nn;
          const int b = sn >> 11, s = sn & (SS - 1);
          Vt[(((size_t)b * HH + h) * DKK + d) * SS + s] = __float2bfloat16(v);
        }
      }
    }
  }
}

// ---------------------------------------------------------------------------
// Output projection GEMM (reg-staged) + T1 XCD remap: 1D grid 512; the 16
// n0-siblings of each m-panel (shared A rows) land on one XCD.
// Bijective: 512 = 8 * 64.  out = Ar @ Wob^T, tile 128m x 64n, BK=64.
// ---------------------------------------------------------------------------
__global__ __launch_bounds__(256) void out_gemm_kernel(
    const bf16* __restrict__ A, const bf16* __restrict__ W,
    float* __restrict__ out) {
  __shared__ __align__(16) bf16 As[128][72];
  __shared__ __align__(16) bf16 Bs[64][72];
  const int t = threadIdx.x;
  const int wave = t >> 6, lane = t & 63;
  const int quad = lane >> 4, l15 = lane & 15;
  const int wm = (wave >> 1) * 64, wn = (wave & 1) * 32;

  const int bid = blockIdx.x;
  const int xcd = bid & 7, slot = bid >> 3;   // slot 0..63
  const int m0 = (xcd + 8 * (slot >> 4)) * 128;  // 32 panels over 8 XCDs
  const int n0 = (slot & 15) * 64;

  const int sr = t >> 2;
  const int sc = (t & 3) * 16;

  v8s ar[4], br[2];
  auto loadA = [&](int kc) {
#pragma unroll
    for (int rr = 0; rr < 2; ++rr) {
      const bf16* p = A + (size_t)(m0 + sr + rr * 64) * DIMM + kc + sc;
#pragma unroll
      for (int i = 0; i < 2; ++i) ar[rr * 2 + i] = ((const v8s*)p)[i];
    }
  };
  auto loadB = [&](int kc) {
    const bf16* p = W + (size_t)(n0 + sr) * DIMM + kc + sc;
#pragma unroll
    for (int i = 0; i < 2; ++i) br[i] = ((const v8s*)p)[i];
  };

  f32x4 acc[4][2] = {};
  loadA(0);
  loadB(0);
  for (int kc = 0; kc < DIMM; kc += 64) {
    __syncthreads();
#pragma unroll
    for (int rr = 0; rr < 2; ++rr) {
      *(v8s*)&As[sr + rr * 64][sc] = ar[rr * 2 + 0];
      *(v8s*)&As[sr + rr * 64][sc + 8] = ar[rr * 2 + 1];
    }
    *(v8s*)&Bs[sr][sc] = br[0];
    *(v8s*)&Bs[sr][sc + 8] = br[1];
    if (kc + 64 < DIMM) {
      loadA(kc + 64);
      loadB(kc + 64);
    }
    __syncthreads();
#pragma unroll
    for (int ks = 0; ks < 2; ++ks) {
      v8s af[4], bfr[2];
#pragma unroll
      for (int i = 0; i < 4; ++i)
        af[i] = *(const v8s*)&As[wm + i * 16 + l15][ks * 32 + quad * 8];
#pragma unroll
      for (int j = 0; j < 2; ++j)
        bfr[j] = *(const v8s*)&Bs[wn + j * 16 + l15][ks * 32 + quad * 8];
#pragma unroll
      for (int i = 0; i < 4; ++i)
#pragma unroll
        for (int j = 0; j < 2; ++j)
          acc[i][j] = __builtin_amdgcn_mfma_f32_16x16x32_bf16(
              af[i], bfr[j], acc[i][j], 0, 0, 0);
    }
  }

#pragma unroll
  for (int i = 0; i < 4; ++i) {
#pragma unroll
    for (int r = 0; r < 4; ++r) {
      const int m = m0 + wm + i * 16 + quad * 4 + r;
#pragma unroll
      for (int j = 0; j < 2; ++j) {
        const int n = n0 + wn + j * 16 + l15;
        out[(size_t)m * DIMM + n] = acc[i][j][r];
      }
    }
  }
}

// ---------------------------------------------------------------------------
// MFMA flash attention v7 EXACT (best measured: 56.5-57.4us).  R4/R5/R7/R8
// all regressed it: swizzle added conflicts; single-buffer serialized
// staging; small blocks doubled staging/FLOP; VALU row-sum moved hidden
// MFMA work onto the busy VALU pipe.  Do not touch the inner loop.
// ---------------------------------------------------------------------------
__global__ __launch_bounds__(512) void attn_kernel(
    const bf16* __restrict__ Qr, const bf16* __restrict__ Kr,
    const bf16* __restrict__ Vt, const unsigned long long* __restrict__ mp,
    bf16* __restrict__ Ar) {
  // smem[0] = K tiles, smem[1] = V tiles; [kv][parity][buf][row][col]
  __shared__ __align__(16) bf16 smem[2][2][2][64][72];

  const int t = threadIdx.x;
  const int wave = t >> 6, lane = t & 63;
  const int l31 = lane & 31, hf = lane >> 5;
  const int qb = wave & 3;   // q sub-block 0..3 (32 rows each)
  const int pr = wave >> 2;  // kt parity: 0 = even kt, 1 = odd kt

  const int bx = blockIdx.x;
  const int xcd = bx & 7, j = bx >> 3;
  const int g = (xcd << 2) | (j & 3);  // (b,h) group 0..31
  const int tile = j >> 2;             // q-tile 0..15 (128 rows each)
  const int hd = g & 15, b = g >> 4;

  const int qw = tile * 128 + qb * 32;  // wave owns 32 q-rows
  const size_t bhv = ((size_t)b * HH + hd) * DKK;

  // Q as B-fragments: lane l31 = q-col, c = cs*16 + 8*hf + i
  v8s bq[4];
  {
    const bf16* qrow = Qr + ((size_t)(b * SS + qw + l31)) * DIMM + hd * 64;
#pragma unroll
    for (int cs = 0; cs < 4; ++cs)
      bq[cs] = *(const v8s*)(qrow + cs * 16 + 8 * hf);
  }

  // ones B-fragment for row-sum MFMA
  v8s vones;
#pragma unroll
  for (int i = 0; i < 8; ++i) vones[i] = (short)0x3F80;

  f32x16 o0 = {}, o1 = {}, ol = {};

  // cooperative staging: 512 threads x 16B per tile, 4 tiles per step
  const int r0 = t >> 3;       // 0..63
  const int c0 = (t & 7) * 8;  // 0..56

  auto gK = [&](int kt) {
    return *(const v8s*)(Kr + ((size_t)(b * SS + kt * 64 + r0)) * DIMM +
                         hd * 64 + c0);
  };
  auto gV = [&](int kt) {
    return *(const v8s*)(Vt + (bhv + r0) * SS + kt * 64 + c0);
  };
  auto loadM = [&](int kt) {
    return mp[((size_t)b * 32 + kt) * SS + qw + l31];
  };

  // prologue: stage kt 0 (par0 buf0) and kt 1 (par1 buf0); prefetch kt 2,3
  {
    const v8s k0 = gK(0), v0 = gV(0), k1 = gK(1), v1 = gV(1);
    *(v8s*)&smem[0][0][0][r0][c0] = k0;
    *(v8s*)&smem[1][0][0][r0][c0] = v0;
    *(v8s*)&smem[0][1][0][r0][c0] = k1;
    *(v8s*)&smem[1][1][0][r0][c0] = v1;
  }
  v8s kpr[2], vpr[2];
  kpr[0] = gK(2);
  vpr[0] = gV(2);
  kpr[1] = gK(3);
  vpr[1] = gV(3);
  unsigned long long mwcur = loadM(pr);

  for (int s = 0; s < 16; ++s) {
    __syncthreads();
    const int nb = (s + 1) & 1;
    if (s < 15) {
      *(v8s*)&smem[0][0][nb][r0][c0] = kpr[0];
      *(v8s*)&smem[1][0][nb][r0][c0] = vpr[0];
      *(v8s*)&smem[0][1][nb][r0][c0] = kpr[1];
      *(v8s*)&smem[1][1][nb][r0][c0] = vpr[1];
      if (s < 14) {
        kpr[0] = gK(2 * s + 4);
        vpr[0] = gV(2 * s + 4);
        kpr[1] = gK(2 * s + 5);
        vpr[1] = gV(2 * s + 5);
      }
    }
    const unsigned long long mwnext = (s < 15) ? loadM(2 * s + 2 + pr) : 0ULL;
    const unsigned long long mq = mwcur >> (4 * hf);
    const int cb = s & 1;

    // ---- QK^T (swapped): st[n] rows = k (n*32 block), col = q = l31 ----
    f32x16 st[2];
#pragma unroll
    for (int n = 0; n < 2; ++n) {
      f32x16 sa = {};
#pragma unroll
      for (int cs = 0; cs < 4; ++cs) {
        const v8s ak =
            *(const v8s*)&smem[0][pr][cb][n * 32 + l31][cs * 16 + 8 * hf];
        sa = __builtin_amdgcn_mfma_f32_32x32x16_bf16(ak, bq[cs], sa, 0, 0, 0);
      }
      st[n] = sa;
    }

    // ---- masked exp2 + pack to bf16 pairs (in-register) ----
    int pd[8][2];
#pragma unroll
    for (int n = 0; n < 2; ++n)
#pragma unroll
      for (int g2 = 0; g2 < 4; ++g2)
#pragma unroll
        for (int jj = 0; jj < 2; ++jj) {
          const int bp = 32 * n + 8 * g2 + 2 * jj;
          const int m = g2 * 4 + 2 * jj;
          const float p0 =
              ((mq >> bp) & 1) ? __builtin_amdgcn_exp2f(st[n][m]) : 0.f;
          const float p1 =
              ((mq >> (bp + 1)) & 1) ? __builtin_amdgcn_exp2f(st[n][m + 1])
                                     : 0.f;
          pd[n * 4 + g2][jj] = cvt_pk_bf16(p0, p1);
        }

    // ---- redistribute to PV A-fragments: 2 permlane32_swap per k-slice ----
    v8s af[4];
#pragma unroll
    for (int ks = 0; ks < 4; ++ks) {
      int a0 = pd[2 * ks][0], b0 = pd[2 * ks + 1][0];
      int a1 = pd[2 * ks][1], b1 = pd[2 * ks + 1][1];
      asm("v_permlane32_swap_b32 %0, %1" : "+v"(a0), "+v"(b0));
      asm("v_permlane32_swap_b32 %0, %1" : "+v"(a1), "+v"(b1));
      int4 w;
      w.x = a0;
      w.y = a1;
      w.z = b0;
      w.w = b1;
      af[ks] = *(v8s*)&w;
    }

    // ---- PV + row-sum ----
#pragma unroll
    for (int ks = 0; ks < 4; ++ks) {
      const v8s bv0 = *(const v8s*)&smem[1][pr][cb][l31][ks * 16 + 8 * hf];
      const v8s bv1 =
          *(const v8s*)&smem[1][pr][cb][32 + l31][ks * 16 + 8 * hf];
      o0 = __builtin_amdgcn_mfma_f32_32x32x16_bf16(af[ks], bv0, o0, 0, 0, 0);
      o1 = __builtin_amdgcn_mfma_f32_32x32x16_bf16(af[ks], bv1, o1, 0, 0, 0);
      ol = __builtin_amdgcn_mfma_f32_32x32x16_bf16(af[ks], vones, ol, 0, 0, 0);
    }
    mwcur = mwnext;
  }

  // ---- cross-parity combine via LDS (exact sum; no running max) ----
  // scratch overlays the (now dead) K/V staging; stride 52 f32 (16B-aligned,
  // 8-bank spread) per lane.
  __syncthreads();
  float* scratch = (float*)&smem[0][0][0][0][0];
  if (wave >= 4) {
    float* dst = scratch + ((size_t)(wave - 4) * 64 + lane) * 52;
#pragma unroll
    for (int i = 0; i < 4; ++i) {
      f32x4 t0 = {o0[4 * i], o0[4 * i + 1], o0[4 * i + 2], o0[4 * i + 3]};
      f32x4 t1 = {o1[4 * i], o1[4 * i + 1], o1[4 * i + 2], o1[4 * i + 3]};
      f32x4 t2 = {ol[4 * i], ol[4 * i + 1], ol[4 * i + 2], ol[4 * i + 3]};
      *(f32x4*)(dst + 4 * i) = t0;
      *(f32x4*)(dst + 16 + 4 * i) = t1;
      *(f32x4*)(dst + 32 + 4 * i) = t2;
    }
  }
  __syncthreads();
  if (wave < 4) {
    const float* src = scratch + ((size_t)wave * 64 + lane) * 52;
#pragma unroll
    for (int m = 0; m < 16; ++m) {
      o0[m] += src[m];
      o1[m] += src[16 + m];
      ol[m] += src[32 + m];
    }
    // ---- epilogue: normalize rows and store flat [q][hd*64 + d] ----
#pragma unroll
    for (int m = 0; m < 16; ++m) {
      const float inv = __builtin_amdgcn_rcpf(ol[m]);
      const int q = qw + (m & 3) + 8 * (m >> 2) + 4 * hf;
      const size_t row = (size_t)b * SS + q;
      Ar[row * DIMM + hd * 64 + l31] = __float2bfloat16(o0[m] * inv);
      Ar[row * DIMM + hd * 64 + 32 + l31] = __float2bfloat16(o1[m] * inv);
    }
  }
}

extern "C" void kernel_launch(void* const* d_in, const int* in_sizes, int n_in,
                              void* d_out, int out_size, void* d_ws,
                              size_t ws_size, hipStream_t stream) {
  const float* dec = (const float*)d_in[0];
  const float* enc = (const float*)d_in[1];
  const float* Wq = (const float*)d_in[2];
  const float* Wkv = (const float*)d_in[3];
  const float* Wo = (const float*)d_in[4];
  const int* mask = (const int*)d_in[5];
  float* out = (float*)d_out;

  // decb/Wqb live in d_out: dead scratch until out_gemm overwrites it.
  bf16* decb = (bf16*)d_out;
  bf16* Wqb = (bf16*)((char*)d_out + ((size_t)2 * SS * DIMM * 2));

  // ws layout (40.4 MB): encb 8 MiB (Ar overlays) | Wkvb 4 | Wob 2 |
  // Qr 8 | Kr 8 | Vt 8 | mp 1
  char* ws = (char*)d_ws;
  size_t off = 0;
  bf16* encb = (bf16*)(ws + off);
  bf16* Ar = (bf16*)(ws + off);   off += (size_t)2 * SS * DIMM * 2;
  bf16* Wkvb = (bf16*)(ws + off); off += (size_t)2 * DIMM * DIMM * 2;
  bf16* Wob = (bf16*)(ws + off);  off += (size_t)DIMM * DIMM * 2;
  bf16* Qr = (bf16*)(ws + off);   off += (size_t)2 * SS * DIMM * 2;
  bf16* Kr = (bf16*)(ws + off);   off += (size_t)2 * SS * DIMM * 2;
  bf16* Vt = (bf16*)(ws + off);   off += (size_t)2 * SS * DIMM * 2;
  unsigned long long* mp = (unsigned long long*)(ws + off);

  dim3 blk(256);
  convert_pack_kernel<<<dim3(1024), blk, 0, stream>>>(
      dec, enc, Wq, Wkv, Wo, mask, decb, encb, Wqb, Wkvb, Wob, mp);
  proj_gemm_kernel<<<dim3(768), blk, 0, stream>>>(decb, encb, Wqb, Wkvb, Qr,
                                                  Kr, Vt);
  attn_kernel<<<dim3(512), dim3(512), 0, stream>>>(Qr, Kr, Vt, mp, Ar);
  out_gemm_kernel<<<dim3(512), blk, 0, stream>>>(Ar, Wob, out);
}